// Round 5
// baseline (194.001 us; speedup 1.0000x reference)
//
#include <hip/hip_runtime.h>

#define E_CNT 1560
#define B_CNT 4
#define N_CNT 40
#define T_CNT 100

typedef __attribute__((ext_vector_type(8))) short bf16x8;
typedef __attribute__((ext_vector_type(4))) float f32x4;

__device__ __forceinline__ short f2bf(float f) {
  union { float f; unsigned u; } v; v.f = f;
  unsigned r = v.u + 0x7FFFu + ((v.u >> 16) & 1u);
  return (short)(r >> 16);
}
__device__ __forceinline__ float bf2f(short s) {
  union { unsigned u; float f; } v; v.u = ((unsigned)(unsigned short)s) << 16;
  return v.f;
}
__device__ __forceinline__ float eluf(float x) { return x > 0.f ? x : (__expf(x) - 1.f); }
__device__ __forceinline__ f32x4 mfma16(bf16x8 a, bf16x8 b, f32x4 c) {
  return __builtin_amdgcn_mfma_f32_16x16x32_bf16(a, b, c, 0, 0, 0);
}
// T2 XOR swizzle: 256B rows, 16B slots permuted by row&7 (write & read both sides)
__device__ __forceinline__ int swz(int row, int bytecol) {
  return row * 256 + (bytecol ^ ((row & 7) << 4));
}

// ---------------- workspace layout (bytes) ----------------
enum : size_t {
  OFF_A1   = 0,                     // [128][64] bf16 conv1 A (bn1 scale folded), col = tap*8+c
  OFF_A2   = OFF_A1 + 16384,        // [5][128][128] bf16 conv2 shifted A (bn2 scale folded)
  OFF_INPB = OFF_A2 + 163840,       // [4*40*100*4] bf16 pre-converted input
  OFF_B1F  = OFF_INPB + 128000,     // [128] f32 folded conv1 bias (sc1*b1)
  OFF_O1   = OFF_B1F + 512,         // [128] f32 bn1 offset
  OFF_B2F  = OFF_O1 + 512,          // [128] f32 folded conv2 bias (sc2*b2)
  OFF_O2   = OFF_B2F + 512,         // [128] f32 bn2 offset
  OFF_BC1  = OFF_O2 + 512,          // [128] f32 folded mlp1 layer-1 bias
  OFF_W1T1 = OFF_BC1 + 512,         // [128][128] bf16 Wc^T = (convp_w^T @ mlp1_w1)^T
  OFF_W1T2 = OFF_W1T1 + 32768,      // [128][128] bf16 mlp1_w2^T
  OFF_W3T1 = OFF_W1T2 + 32768,      // [128][384] bf16 mlp3_w1^T
  OFF_W3T2 = OFF_W3T1 + 98304,      // [128][128] bf16 mlp3_w2^T
  OFF_RIDX = OFF_W3T2 + 32768,      // [1560] int
  OFF_SIDX = OFF_RIDX + 6400,
  OFF_EF   = OFF_SIDX + 6400,       // [6240][128] bf16 attention-pooled h2 (hsum)
  OFF_XSK  = OFF_EF + 1597440,      // [6240][128] bf16 x_skip
  OFF_XN   = OFF_XSK + 1597440,     // [160][128] bf16 node features
  WS_NEED  = OFF_XN + 40960
};

// ---------------- prep: repack weights, fold BN scale+convp, cvt input, decode edges ----------------
__global__ void k_prep(
    const float* __restrict__ inp,
    const float* __restrict__ c1w, const float* __restrict__ c1b,
    const float* __restrict__ c2w, const float* __restrict__ c2b,
    const float* __restrict__ cpw, const float* __restrict__ cpb,
    const float* __restrict__ g1, const float* __restrict__ be1, const float* __restrict__ m1, const float* __restrict__ v1,
    const float* __restrict__ g2, const float* __restrict__ be2, const float* __restrict__ m2, const float* __restrict__ v2,
    const float* __restrict__ m1w1, const float* __restrict__ m1b1, const float* __restrict__ m1w2,
    const float* __restrict__ m3w1, const float* __restrict__ m3w2,
    const float* __restrict__ relr, const float* __restrict__ rels,
    short* __restrict__ A1, short* __restrict__ A2, short* __restrict__ inpb,
    float* __restrict__ b1f, float* __restrict__ o1, float* __restrict__ b2f, float* __restrict__ o2,
    float* __restrict__ bc1,
    short* __restrict__ w1t1, short* __restrict__ w1t2, short* __restrict__ w3t1, short* __restrict__ w3t2,
    int* __restrict__ ridx, int* __restrict__ sidx)
{
  const int id = blockIdx.x * blockDim.x + threadIdx.x;
  const int NTH = gridDim.x * blockDim.x;
  // conv1 A with bn1 scale folded: col = tap*8 + c (cols with tap>=5 are zero)
  for (int i = id; i < 8192; i += NTH) {
    int co = i >> 6, col = i & 63, k = col >> 3, c = col & 7;
    float sa = g1[co] * rsqrtf(v1[co] + 1e-5f);
    A1[i] = (k < 5) ? f2bf(c1w[co * 40 + c * 5 + k] * sa) : (short)0;
  }
  // conv2 A with bn2 scale folded
  for (int i = id; i < 81920; i += NTH) {
    int s = i >> 14, rem = i & 16383, co = rem >> 7, ci = rem & 127;
    float sb = g2[co] * rsqrtf(v2[co] + 1e-5f);
    A2[i] = f2bf(c2w[(co * 128 + ci) * 5 + s] * sb);
  }
  for (int i = id; i < 64000; i += NTH) inpb[i] = f2bf(inp[i]);
  for (int i = id; i < 128; i += NTH) {
    float sa = g1[i] * rsqrtf(v1[i] + 1e-5f);
    b1f[i] = c1b[i] * sa; o1[i] = be1[i] - m1[i] * sa;
    float sb = g2[i] * rsqrtf(v2[i] + 1e-5f);
    b2f[i] = c2b[i] * sb; o2[i] = be2[i] - m2[i] * sb;
  }
  // Wc^T: w1t1[c*128+i] = sum_o cpw[o*128+i] * m1w1[o*128+c]  (convp folded into mlp1 L1)
  for (int idx = id; idx < 16384; idx += NTH) {
    int c = idx >> 7, i = idx & 127;
    float s = 0.f;
    for (int o = 0; o < 128; ++o) s += cpw[o * 128 + i] * m1w1[o * 128 + c];
    w1t1[idx] = f2bf(s);
  }
  // bc1[c] = m1b1[c] + (1/44) * sum_o cpb[o] * m1w1[o*128+c]
  for (int c = id; c < 128; c += NTH) {
    float s = 0.f;
    for (int o = 0; o < 128; ++o) s += cpb[o] * m1w1[o * 128 + c];
    bc1[c] = m1b1[c] + s * (1.0f / 44.0f);
  }
  for (int i = id; i < 16384; i += NTH) {
    int co = i >> 7, k = i & 127;
    w1t2[i] = f2bf(m1w2[k * 128 + co]);
    w3t2[i] = f2bf(m3w2[k * 128 + co]);
  }
  for (int i = id; i < 49152; i += NTH) {
    int co = i / 384, k = i - co * 384;
    w3t1[i] = f2bf(m3w1[k * 128 + co]);
  }
  for (int i = id; i < E_CNT; i += NTH) {
    int rr = 0, ss = 0;
    for (int n = 0; n < N_CNT; ++n) {
      if (relr[i * N_CNT + n] > 0.5f) rr = n;
      if (rels[i * N_CNT + n] > 0.5f) ss = n;
    }
    ridx[i] = rr; sidx[i] = ss;
  }
}

// ---------------- fused per-edge temporal CNN: 2 edges/block, m=4 per wave ----------------
// wave w: edge e = w>>1, channel-half h = w&1 (rows 64h..64h+63)
__global__ __launch_bounds__(256, 4) void k_cnn(
    const short* __restrict__ inpb,
    const short* __restrict__ A1, const short* __restrict__ A2,
    const float* __restrict__ b1fv, const float* __restrict__ o1v,
    const float* __restrict__ b2fv, const float* __restrict__ o2v,
    const float* __restrict__ wa,
    const int* __restrict__ ridx, const int* __restrict__ sidx,
    short* __restrict__ ef)
{
  __shared__ short h1t[2][52 * 128];   // pooled conv1 out [t][ci], XOR-swizzled, rows 48-51 pad
  __shared__ float lgp[2][2][48];      // conva logit partials per (edge, half)
  __shared__ float attnS[2][48];       // softmax/44 weights

  const int tid = threadIdx.x;
  const int lane = tid & 63;
  const int w = tid >> 6;
  const int g = lane >> 4;
  const int lr = lane & 15;
  const int e = w >> 1;        // this wave's edge
  const int h = w & 1;         // this wave's channel half (64 rows)

  const int eg0 = blockIdx.x * 2;
  const int b = eg0 / E_CNT;
  const int e0 = eg0 - b * E_CNT;
  const short* nbase = inpb + (size_t)b * N_CNT * 400;
  const short* nS = nbase + sidx[e0 + e] * 400;
  const short* nR = nbase + ridx[e0 + e] * 400;

  // zero pad rows 48-51 of both h1t (written before the phase-1-end barrier)
  {
    int ee = tid >> 7, off = (tid & 127) * 4;
    *(short4*)&h1t[ee][48 * 128 + off] = make_short4(0, 0, 0, 0);
  }

  // ---- phase 1: conv1 (scale-folded) + bias/relu + offset + maxpool2 -> h1t[e] ----
  {
    bf16x8 a1f[2][4];
#pragma unroll
    for (int ks = 0; ks < 2; ++ks)
#pragma unroll
      for (int m = 0; m < 4; ++m)
        a1f[ks][m] = *(const bf16x8*)(A1 + (64 * h + 16 * m + lr) * 64 + ks * 32 + 8 * g);
#pragma unroll
    for (int n = 0; n < 6; ++n) {
      f32x4 acc[4];
#pragma unroll
      for (int m = 0; m < 4; ++m) acc[m] = f32x4{0.f, 0.f, 0.f, 0.f};
#pragma unroll
      for (int ks = 0; ks < 2; ++ks) {
        int tc = n * 16 + lr + 4 * ks + g;   // tap = 4ks+g; taps 5-7 hit zero A cols
        tc = tc > 99 ? 99 : tc;
        short4 sv = *(const short4*)(nS + tc * 4);
        short4 rv = *(const short4*)(nR + tc * 4);
        bf16x8 bfr;
        bfr[0] = sv.x; bfr[1] = sv.y; bfr[2] = sv.z; bfr[3] = sv.w;
        bfr[4] = rv.x; bfr[5] = rv.y; bfr[6] = rv.z; bfr[7] = rv.w;
#pragma unroll
        for (int m = 0; m < 4; ++m) acc[m] = mfma16(a1f[ks][m], bfr, acc[m]);
      }
#pragma unroll
      for (int m = 0; m < 4; ++m) {
        int rb = 64 * h + 16 * m + 4 * g;
        f32x4 bc = *(const f32x4*)(b1fv + rb);
        f32x4 oc = *(const f32x4*)(o1v + rb);
        short pv[4];
#pragma unroll
        for (int r = 0; r < 4; ++r) {
          float v = fmaxf(acc[m][r] + bc[r], 0.f) + oc[r];
          float o = __shfl_xor(v, 1);
          pv[r] = f2bf(fmaxf(v, o));
        }
        if ((lane & 1) == 0) {
          int t = 8 * n + (lr >> 1);
          *(short4*)((char*)h1t[e] + swz(t, rb * 2)) = make_short4(pv[0], pv[1], pv[2], pv[3]);
        }
      }
    }
  }
  __syncthreads();

  // ---- phase 2: conv2 = 5 shifted GEMMs; wave computes 64 rows x 48 cols of its edge ----
  f32x4 acc[4][3];   // [m][n]
#pragma unroll
  for (int m = 0; m < 4; ++m)
#pragma unroll
    for (int n = 0; n < 3; ++n) acc[m][n] = f32x4{0.f, 0.f, 0.f, 0.f};
  {
    const short* a2b = A2 + (64 * h + lr) * 128 + 8 * g;
#pragma unroll
    for (int sh = 0; sh < 5; ++sh) {
#pragma unroll
      for (int ks = 0; ks < 4; ++ks) {
        bf16x8 af[4];
#pragma unroll
        for (int m = 0; m < 4; ++m)
          af[m] = *(const bf16x8*)(a2b + sh * 16384 + m * 16 * 128 + ks * 32);
#pragma unroll
        for (int n = 0; n < 3; ++n) {
          bf16x8 bfr = *(const bf16x8*)((char*)h1t[e] + swz(n * 16 + lr + sh, ks * 64 + 16 * g));
#pragma unroll
          for (int m = 0; m < 4; ++m) acc[m][n] = mfma16(af[m], bfr, acc[m][n]);
        }
      }
    }
  }

  // ---- bias/relu/offset in-register + conva logits ----
  {
    float lg[3] = {0.f, 0.f, 0.f};
#pragma unroll
    for (int m = 0; m < 4; ++m) {
      int rb = 64 * h + 16 * m + 4 * g;
      f32x4 bc = *(const f32x4*)(b2fv + rb);
      f32x4 oc = *(const f32x4*)(o2v + rb);
      f32x4 wm = *(const f32x4*)(wa + rb);
#pragma unroll
      for (int n = 0; n < 3; ++n) {
#pragma unroll
        for (int r = 0; r < 4; ++r) {
          float v = fmaxf(acc[m][n][r] + bc[r], 0.f) + oc[r];
          acc[m][n][r] = v;          // h2 value, kept f32 in-register
          lg[n] += wm[r] * v;
        }
      }
    }
#pragma unroll
    for (int n = 0; n < 3; ++n) {
      float p = lg[n];
      p += __shfl_xor(p, 16);
      p += __shfl_xor(p, 32);
      if (g == 0) lgp[e][h][n * 16 + lr] = p;
    }
  }
  __syncthreads();

  // ---- softmax over t (waves 0,1 handle edge 0,1), fold the /44 of the mean ----
  if (w < 2) {
    int ee = w;
    float x = -3e38f;
    if (lane < 44) x = lgp[ee][0][lane] + lgp[ee][1][lane];
    float mx = x;
#pragma unroll
    for (int d = 32; d; d >>= 1) mx = fmaxf(mx, __shfl_xor(mx, d));
    float ex = (lane < 44) ? __expf(x - mx) : 0.f;
    float sm = ex;
#pragma unroll
    for (int d = 32; d; d >>= 1) sm += __shfl_xor(sm, d);
    if (lane < 48) attnS[ee][lane] = (lane < 44) ? ex / (sm * 44.f) : 0.f;
  }
  __syncthreads();

  // ---- attention-weighted pool (in-register) -> ef = hsum ----
#pragma unroll
  for (int m = 0; m < 4; ++m) {
    f32x4 red = f32x4{0.f, 0.f, 0.f, 0.f};
#pragma unroll
    for (int n = 0; n < 3; ++n) {
      float aw = attnS[e][n * 16 + lr];
      red += acc[m][n] * aw;
    }
    short pv[4];
#pragma unroll
    for (int r = 0; r < 4; ++r) {
      float p = red[r];
      p += __shfl_xor(p, 1);
      p += __shfl_xor(p, 2);
      p += __shfl_xor(p, 4);
      p += __shfl_xor(p, 8);
      pv[r] = f2bf(p);
    }
    if (lr == 0)
      *(short4*)(ef + (size_t)(eg0 + e) * 128 + 64 * h + 16 * m + 4 * g) =
          make_short4(pv[0], pv[1], pv[2], pv[3]);
  }
}

// ---------------- mlp1 (two-layer, per-edge; L1 weight = folded convp@W1) -> x_skip ----------------
__global__ __launch_bounds__(256, 2) void k_mlp1(
    const short* __restrict__ ef,
    const short* __restrict__ w1t, const float* __restrict__ b1,
    const short* __restrict__ w2t, const float* __restrict__ b2,
    short* __restrict__ xskip)
{
  __shared__ short hbuf[16 * 136];
  __shared__ short obuf[16 * 128];
  const int tid = threadIdx.x, lane = tid & 63, w = tid >> 6, g = lane >> 4, lr = lane & 15;
  const int mbase = blockIdx.x * 16;

  f32x4 acc[2];
  acc[0] = f32x4{0.f, 0.f, 0.f, 0.f};
  acc[1] = f32x4{0.f, 0.f, 0.f, 0.f};
#pragma unroll
  for (int ks = 0; ks < 4; ++ks) {
    bf16x8 afr = *(const bf16x8*)(ef + (size_t)(mbase + lr) * 128 + ks * 32 + 8 * g);
#pragma unroll
    for (int ni = 0; ni < 2; ++ni) {
      int co = (2 * w + ni) * 16 + lr;
      bf16x8 bfr = *(const bf16x8*)(w1t + co * 128 + ks * 32 + 8 * g);
      acc[ni] = mfma16(afr, bfr, acc[ni]);
    }
  }
#pragma unroll
  for (int ni = 0; ni < 2; ++ni) {
    int co = (2 * w + ni) * 16 + lr;
    float bias = b1[co];
#pragma unroll
    for (int r = 0; r < 4; ++r) hbuf[(4 * g + r) * 136 + co] = f2bf(eluf(acc[ni][r] + bias));
  }
  __syncthreads();
  acc[0] = f32x4{0.f, 0.f, 0.f, 0.f};
  acc[1] = f32x4{0.f, 0.f, 0.f, 0.f};
#pragma unroll
  for (int ks = 0; ks < 4; ++ks) {
    bf16x8 afr = *(const bf16x8*)&hbuf[lr * 136 + ks * 32 + 8 * g];
#pragma unroll
    for (int ni = 0; ni < 2; ++ni) {
      int co = (2 * w + ni) * 16 + lr;
      bf16x8 bfr = *(const bf16x8*)(w2t + co * 128 + ks * 32 + 8 * g);
      acc[ni] = mfma16(afr, bfr, acc[ni]);
    }
  }
#pragma unroll
  for (int ni = 0; ni < 2; ++ni) {
    int co = (2 * w + ni) * 16 + lr;
    float bias = b2[co];
#pragma unroll
    for (int r = 0; r < 4; ++r) obuf[(4 * g + r) * 128 + co] = f2bf(eluf(acc[ni][r] + bias));
  }
  __syncthreads();
  *(bf16x8*)(xskip + (size_t)mbase * 128 + tid * 8) = *(const bf16x8*)&obuf[tid * 8];
}

// ---------------- edge2node mean + mlp2 (cooperative edge compaction) ----------------
__global__ __launch_bounds__(128, 4) void k_node(
    const short* __restrict__ xskip, const int* __restrict__ ridx,
    const float* __restrict__ w1, const float* __restrict__ b1,
    const float* __restrict__ w2, const float* __restrict__ b2,
    short* __restrict__ xn)
{
  __shared__ float incs[128];
  __shared__ float hb[128];
  __shared__ int lst[64];
  __shared__ int lcnt;
  const int tid = threadIdx.x;
  const int bn_ = blockIdx.x;
  const int b = bn_ / N_CNT, n = bn_ - b * N_CNT;
  if (tid == 0) lcnt = 0;
  __syncthreads();
  for (int e2 = tid; e2 < E_CNT; e2 += 128) {
    if (ridx[e2] == n) {
      int p = atomicAdd(&lcnt, 1);
      if (p < 64) lst[p] = e2;
    }
  }
  __syncthreads();
  const int m_ = lcnt < 64 ? lcnt : 64;
  const short* base = xskip + (size_t)b * E_CNT * 128 + tid;
  float acc = 0.f;
  for (int i = 0; i < m_; ++i) acc += bf2f(base[(size_t)lst[i] * 128]);
  incs[tid] = acc * 0.025f;  // / N
  __syncthreads();
  float h = b1[tid];
  for (int k = 0; k < 128; ++k) h += incs[k] * w1[k * 128 + tid];
  hb[tid] = eluf(h);
  __syncthreads();
  float h2 = b2[tid];
  for (int k = 0; k < 128; ++k) h2 += hb[k] * w2[k * 128 + tid];
  xn[(size_t)bn_ * 128 + tid] = f2bf(eluf(h2));
}

// ---------------- gather(sn,rc,skip) + mlp3 + fc_out ----------------
__global__ __launch_bounds__(256, 2) void k_final(
    const short* __restrict__ xn, const short* __restrict__ xskip,
    const int* __restrict__ ridx, const int* __restrict__ sidx,
    const short* __restrict__ w1t, const float* __restrict__ b1,
    const short* __restrict__ w2t, const float* __restrict__ b2,
    const float* __restrict__ fcw, const float* __restrict__ fcb,
    float* __restrict__ out)
{
  __shared__ short hbuf[16 * 136];
  __shared__ short h2buf[16 * 136];
  const int tid = threadIdx.x, lane = tid & 63, w = tid >> 6, g = lane >> 4, lr = lane & 15;
  const int mbase = blockIdx.x * 16;
  const int row = mbase + lr;
  const int b = row / E_CNT;
  const int e = row - b * E_CNT;
  const short* aS = xn + (size_t)(b * N_CNT + sidx[e]) * 128;
  const short* aR = xn + (size_t)(b * N_CNT + ridx[e]) * 128;
  const short* aK = xskip + (size_t)row * 128;

  f32x4 acc[2];
  acc[0] = f32x4{0.f, 0.f, 0.f, 0.f};
  acc[1] = f32x4{0.f, 0.f, 0.f, 0.f};
#pragma unroll
  for (int ks = 0; ks < 12; ++ks) {
    int k = ks * 32 + 8 * g;
    const short* ap = (k < 128) ? (aS + k) : (k < 256) ? (aR + (k - 128)) : (aK + (k - 256));
    bf16x8 afr = *(const bf16x8*)ap;
#pragma unroll
    for (int ni = 0; ni < 2; ++ni) {
      int co = (2 * w + ni) * 16 + lr;
      bf16x8 bfr = *(const bf16x8*)(w1t + co * 384 + ks * 32 + 8 * g);
      acc[ni] = mfma16(afr, bfr, acc[ni]);
    }
  }
#pragma unroll
  for (int ni = 0; ni < 2; ++ni) {
    int co = (2 * w + ni) * 16 + lr;
    float bias = b1[co];
#pragma unroll
    for (int r = 0; r < 4; ++r) hbuf[(4 * g + r) * 136 + co] = f2bf(eluf(acc[ni][r] + bias));
  }
  __syncthreads();
  acc[0] = f32x4{0.f, 0.f, 0.f, 0.f};
  acc[1] = f32x4{0.f, 0.f, 0.f, 0.f};
#pragma unroll
  for (int ks = 0; ks < 4; ++ks) {
    bf16x8 afr = *(const bf16x8*)&hbuf[lr * 136 + ks * 32 + 8 * g];
#pragma unroll
    for (int ni = 0; ni < 2; ++ni) {
      int co = (2 * w + ni) * 16 + lr;
      bf16x8 bfr = *(const bf16x8*)(w2t + co * 128 + ks * 32 + 8 * g);
      acc[ni] = mfma16(afr, bfr, acc[ni]);
    }
  }
#pragma unroll
  for (int ni = 0; ni < 2; ++ni) {
    int co = (2 * w + ni) * 16 + lr;
    float bias = b2[co];
#pragma unroll
    for (int r = 0; r < 4; ++r) h2buf[(4 * g + r) * 136 + co] = f2bf(eluf(acc[ni][r] + bias));
  }
  __syncthreads();
  if (tid < 32) {
    int e2 = tid >> 1, o = tid & 1;
    float s = fcb[o];
    for (int k = 0; k < 128; ++k) s += bf2f(h2buf[e2 * 136 + k]) * fcw[k * 2 + o];
    out[(size_t)(mbase + e2) * 2 + o] = s;
  }
}

extern "C" void kernel_launch(void* const* d_in, const int* in_sizes, int n_in,
                              void* d_out, int out_size, void* d_ws, size_t ws_size,
                              hipStream_t stream) {
  (void)in_sizes; (void)n_in; (void)out_size; (void)ws_size;
  const float* inp  = (const float*)d_in[0];
  const float* relr = (const float*)d_in[1];
  const float* rels = (const float*)d_in[2];
  const float* c1w  = (const float*)d_in[3];
  const float* c1b  = (const float*)d_in[4];
  const float* g1   = (const float*)d_in[5];
  const float* be1  = (const float*)d_in[6];
  const float* m1   = (const float*)d_in[7];
  const float* v1   = (const float*)d_in[8];
  const float* c2w  = (const float*)d_in[9];
  const float* c2b  = (const float*)d_in[10];
  const float* g2   = (const float*)d_in[11];
  const float* be2  = (const float*)d_in[12];
  const float* m2   = (const float*)d_in[13];
  const float* v2   = (const float*)d_in[14];
  const float* cpw  = (const float*)d_in[15];
  const float* cpb  = (const float*)d_in[16];
  const float* caw  = (const float*)d_in[17];
  // d_in[18] = conva_b: softmax shift-invariant, unused
  const float* m1w1 = (const float*)d_in[19];
  const float* m1b1 = (const float*)d_in[20];
  const float* m1w2 = (const float*)d_in[21];
  const float* m1b2 = (const float*)d_in[22];
  const float* m2w1 = (const float*)d_in[23];
  const float* m2b1 = (const float*)d_in[24];
  const float* m2w2 = (const float*)d_in[25];
  const float* m2b2 = (const float*)d_in[26];
  const float* m3w1 = (const float*)d_in[27];
  const float* m3b1 = (const float*)d_in[28];
  const float* m3w2 = (const float*)d_in[29];
  const float* m3b2 = (const float*)d_in[30];
  const float* fcw  = (const float*)d_in[31];
  const float* fcb  = (const float*)d_in[32];
  float* out = (float*)d_out;

  char* ws = (char*)d_ws;
  short* A1   = (short*)(ws + OFF_A1);
  short* A2   = (short*)(ws + OFF_A2);
  short* inpb = (short*)(ws + OFF_INPB);
  float* b1f  = (float*)(ws + OFF_B1F);
  float* o1   = (float*)(ws + OFF_O1);
  float* b2f  = (float*)(ws + OFF_B2F);
  float* o2   = (float*)(ws + OFF_O2);
  float* bc1  = (float*)(ws + OFF_BC1);
  short* w1t1 = (short*)(ws + OFF_W1T1);
  short* w1t2 = (short*)(ws + OFF_W1T2);
  short* w3t1 = (short*)(ws + OFF_W3T1);
  short* w3t2 = (short*)(ws + OFF_W3T2);
  int*   ridx = (int*)(ws + OFF_RIDX);
  int*   sidx = (int*)(ws + OFF_SIDX);
  short* ef   = (short*)(ws + OFF_EF);
  short* xsk  = (short*)(ws + OFF_XSK);
  short* xn   = (short*)(ws + OFF_XN);

  k_prep<<<256, 256, 0, stream>>>(inp, c1w, c1b, c2w, c2b, cpw, cpb,
                                  g1, be1, m1, v1, g2, be2, m2, v2,
                                  m1w1, m1b1, m1w2, m3w1, m3w2, relr, rels,
                                  A1, A2, inpb, b1f, o1, b2f, o2, bc1,
                                  w1t1, w1t2, w3t1, w3t2, ridx, sidx);
  k_cnn<<<B_CNT * E_CNT / 2, 256, 0, stream>>>(inpb, A1, A2, b1f, o1, b2f, o2,
                                               caw, ridx, sidx, ef);
  k_mlp1<<<390, 256, 0, stream>>>(ef, w1t1, bc1, w1t2, m1b2, xsk);
  k_node<<<B_CNT * N_CNT, 128, 0, stream>>>(xsk, ridx, m2w1, m2b1, m2w2, m2b2, xn);
  k_final<<<390, 256, 0, stream>>>(xn, xsk, ridx, sidx, w3t1, m3b1, w3t2, m3b2, fcw, fcb, out);
}

// Round 6
// 131.888 us; speedup vs baseline: 1.4710x; 1.4710x over previous
//
#include <hip/hip_runtime.h>

#define E_CNT 1560
#define B_CNT 4
#define N_CNT 40
#define T_CNT 100

typedef __attribute__((ext_vector_type(8))) short bf16x8;
typedef __attribute__((ext_vector_type(4))) float f32x4;

__device__ __forceinline__ short f2bf(float f) {
  union { float f; unsigned u; } v; v.f = f;
  unsigned r = v.u + 0x7FFFu + ((v.u >> 16) & 1u);
  return (short)(r >> 16);
}
__device__ __forceinline__ float bf2f(short s) {
  union { unsigned u; float f; } v; v.u = ((unsigned)(unsigned short)s) << 16;
  return v.f;
}
__device__ __forceinline__ float eluf(float x) { return x > 0.f ? x : (__expf(x) - 1.f); }
__device__ __forceinline__ f32x4 mfma16(bf16x8 a, bf16x8 b, f32x4 c) {
  return __builtin_amdgcn_mfma_f32_16x16x32_bf16(a, b, c, 0, 0, 0);
}
// T2 XOR swizzle: 256B rows, 16B slots permuted by row&7 (write & read both sides)
__device__ __forceinline__ int swz(int row, int bytecol) {
  return row * 256 + (bytecol ^ ((row & 7) << 4));
}

// ---------------- workspace layout (bytes) ----------------
enum : size_t {
  OFF_A1   = 0,                     // [128][64] bf16 conv1 A (bn1 scale folded), col = tap*8+c
  OFF_A2   = OFF_A1 + 16384,        // [5][128][128] bf16 conv2 shifted A (bn2 scale folded)
  OFF_INPB = OFF_A2 + 163840,       // [4*40*100*4] bf16 pre-converted input
  OFF_B1F  = OFF_INPB + 128000,     // [128] f32 folded conv1 bias (sc1*b1)
  OFF_O1   = OFF_B1F + 512,         // [128] f32 bn1 offset
  OFF_B2F  = OFF_O1 + 512,          // [128] f32 folded conv2 bias (sc2*b2)
  OFF_O2   = OFF_B2F + 512,         // [128] f32 bn2 offset
  OFF_BC1  = OFF_O2 + 512,          // [128] f32 folded mlp1 layer-1 bias
  OFF_W1T1 = OFF_BC1 + 512,         // [128][128] bf16 Wc^T = (convp_w^T @ mlp1_w1)^T
  OFF_W1T2 = OFF_W1T1 + 32768,      // [128][128] bf16 mlp1_w2^T
  OFF_W3T1 = OFF_W1T2 + 32768,      // [128][384] bf16 mlp3_w1^T
  OFF_W3T2 = OFF_W3T1 + 98304,      // [128][128] bf16 mlp3_w2^T
  OFF_RIDX = OFF_W3T2 + 32768,      // [1560] int
  OFF_SIDX = OFF_RIDX + 6400,
  OFF_EF   = OFF_SIDX + 6400,       // [6240][128] bf16 attention-pooled h2 (hsum)
  OFF_XSK  = OFF_EF + 1597440,      // [6240][128] bf16 x_skip
  OFF_XN   = OFF_XSK + 1597440,     // [160][128] bf16 node features
  WS_NEED  = OFF_XN + 40960
};

// ---------------- prep: repack weights, fold BN scale+convp, cvt input, decode edges ----------------
__global__ void k_prep(
    const float* __restrict__ inp,
    const float* __restrict__ c1w, const float* __restrict__ c1b,
    const float* __restrict__ c2w, const float* __restrict__ c2b,
    const float* __restrict__ cpw, const float* __restrict__ cpb,
    const float* __restrict__ g1, const float* __restrict__ be1, const float* __restrict__ m1, const float* __restrict__ v1,
    const float* __restrict__ g2, const float* __restrict__ be2, const float* __restrict__ m2, const float* __restrict__ v2,
    const float* __restrict__ m1w1, const float* __restrict__ m1b1, const float* __restrict__ m1w2,
    const float* __restrict__ m3w1, const float* __restrict__ m3w2,
    const float* __restrict__ relr, const float* __restrict__ rels,
    short* __restrict__ A1, short* __restrict__ A2, short* __restrict__ inpb,
    float* __restrict__ b1f, float* __restrict__ o1, float* __restrict__ b2f, float* __restrict__ o2,
    float* __restrict__ bc1,
    short* __restrict__ w1t1, short* __restrict__ w1t2, short* __restrict__ w3t1, short* __restrict__ w3t2,
    int* __restrict__ ridx, int* __restrict__ sidx)
{
  const int id = blockIdx.x * blockDim.x + threadIdx.x;
  const int NTH = gridDim.x * blockDim.x;
  // conv1 A with bn1 scale folded: col = tap*8 + c (cols with tap>=5 are zero)
  for (int i = id; i < 8192; i += NTH) {
    int co = i >> 6, col = i & 63, k = col >> 3, c = col & 7;
    float sa = g1[co] * rsqrtf(v1[co] + 1e-5f);
    A1[i] = (k < 5) ? f2bf(c1w[co * 40 + c * 5 + k] * sa) : (short)0;
  }
  // conv2 A with bn2 scale folded
  for (int i = id; i < 81920; i += NTH) {
    int s = i >> 14, rem = i & 16383, co = rem >> 7, ci = rem & 127;
    float sb = g2[co] * rsqrtf(v2[co] + 1e-5f);
    A2[i] = f2bf(c2w[(co * 128 + ci) * 5 + s] * sb);
  }
  for (int i = id; i < 64000; i += NTH) inpb[i] = f2bf(inp[i]);
  for (int i = id; i < 128; i += NTH) {
    float sa = g1[i] * rsqrtf(v1[i] + 1e-5f);
    b1f[i] = c1b[i] * sa; o1[i] = be1[i] - m1[i] * sa;
    float sb = g2[i] * rsqrtf(v2[i] + 1e-5f);
    b2f[i] = c2b[i] * sb; o2[i] = be2[i] - m2[i] * sb;
  }
  // Wc^T: w1t1[c*128+i] = sum_o cpw[o*128+i] * m1w1[o*128+c]  (convp folded into mlp1 L1)
  for (int idx = id; idx < 16384; idx += NTH) {
    int c = idx >> 7, i = idx & 127;
    float s = 0.f;
    for (int o = 0; o < 128; ++o) s += cpw[o * 128 + i] * m1w1[o * 128 + c];
    w1t1[idx] = f2bf(s);
  }
  // bc1[c] = m1b1[c] + (1/44) * sum_o cpb[o] * m1w1[o*128+c]
  for (int c = id; c < 128; c += NTH) {
    float s = 0.f;
    for (int o = 0; o < 128; ++o) s += cpb[o] * m1w1[o * 128 + c];
    bc1[c] = m1b1[c] + s * (1.0f / 44.0f);
  }
  for (int i = id; i < 16384; i += NTH) {
    int co = i >> 7, k = i & 127;
    w1t2[i] = f2bf(m1w2[k * 128 + co]);
    w3t2[i] = f2bf(m3w2[k * 128 + co]);
  }
  for (int i = id; i < 49152; i += NTH) {
    int co = i / 384, k = i - co * 384;
    w3t1[i] = f2bf(m3w1[k * 128 + co]);
  }
  for (int i = id; i < E_CNT; i += NTH) {
    int rr = 0, ss = 0;
    for (int n = 0; n < N_CNT; ++n) {
      if (relr[i * N_CNT + n] > 0.5f) rr = n;
      if (rels[i * N_CNT + n] > 0.5f) ss = n;
    }
    ridx[i] = rr; sidx[i] = ss;
  }
}

// ---------------- fused per-edge temporal CNN: 2 edges/block, m=2 per wave (R4 partition) ----------------
__global__ __launch_bounds__(256, 4) void k_cnn(
    const short* __restrict__ inpb,
    const short* __restrict__ A1, const short* __restrict__ A2,
    const float* __restrict__ b1fv, const float* __restrict__ o1v,
    const float* __restrict__ b2fv, const float* __restrict__ o2v,
    const float* __restrict__ wa,
    const int* __restrict__ ridx, const int* __restrict__ sidx,
    short* __restrict__ ef)
{
  __shared__ short h1t[2][52 * 128];   // pooled conv1 out [t][ci], XOR-swizzled, rows 48-51 pad
  __shared__ short rawb[4 * 408];      // staged node series [S0|R0|S1|R1][400] (+8 pad, 16B-aligned rows)
  __shared__ float lgp[2][4][48];      // conva logit partials per (edge, wave)
  __shared__ float attnS[2][48];       // softmax/44 weights

  const int tid = threadIdx.x;
  const int lane = tid & 63;
  const int w = tid >> 6;
  const int g = lane >> 4;
  const int lr = lane & 15;

  const int eg0 = blockIdx.x * 2;
  const int b = eg0 / E_CNT;
  const int e0 = eg0 - b * E_CNT;
  const short* nbase = inpb + (size_t)b * N_CNT * 400;

  // ---- phase 0: stage 4 node rows (3.2 KB) into LDS with coalesced 16B loads ----
  if (tid < 200) {
    int row = tid / 50, off = (tid % 50) * 8;
    int e = row >> 1;
    int node = (row & 1) ? ridx[e0 + e] : sidx[e0 + e];
    *(bf16x8*)&rawb[row * 408 + off] = *(const bf16x8*)(nbase + node * 400 + off);
  }
  // zero pad rows 48-51 of both h1t (ordered by the staging barrier below)
  {
    int ee = tid >> 7, off = (tid & 127) * 4;
    *(short4*)&h1t[ee][48 * 128 + off] = make_short4(0, 0, 0, 0);
  }
  __syncthreads();

  // ---- phase 1: conv1 (scale-folded) + relu-fold + offset + maxpool2 -> h1t[e] ----
  {
    bf16x8 a1f[2][2];
#pragma unroll
    for (int ks = 0; ks < 2; ++ks)
#pragma unroll
      for (int m = 0; m < 2; ++m)
        a1f[ks][m] = *(const bf16x8*)(A1 + (32 * w + 16 * m + lr) * 64 + ks * 32 + 8 * g);
    f32x4 bc[2], oc[2];
#pragma unroll
    for (int m = 0; m < 2; ++m) {
      int rb = 32 * w + 16 * m + 4 * g;
      bc[m] = *(const f32x4*)(b1fv + rb);
      oc[m] = *(const f32x4*)(o1v + rb);
    }
#pragma unroll
    for (int e = 0; e < 2; ++e) {
#pragma unroll
      for (int n = 0; n < 6; ++n) {
        f32x4 acc[2];
        acc[0] = f32x4{0.f, 0.f, 0.f, 0.f};
        acc[1] = f32x4{0.f, 0.f, 0.f, 0.f};
#pragma unroll
        for (int ks = 0; ks < 2; ++ks) {
          int tc = n * 16 + lr + 4 * ks + g;   // tap = 4ks+g; taps 5-7 hit zero A cols
          tc = tc > 99 ? 99 : tc;
          short4 sv = *(const short4*)&rawb[(2 * e) * 408 + tc * 4];
          short4 rv = *(const short4*)&rawb[(2 * e + 1) * 408 + tc * 4];
          bf16x8 bfr;
          bfr[0] = sv.x; bfr[1] = sv.y; bfr[2] = sv.z; bfr[3] = sv.w;
          bfr[4] = rv.x; bfr[5] = rv.y; bfr[6] = rv.z; bfr[7] = rv.w;
#pragma unroll
          for (int m = 0; m < 2; ++m) acc[m] = mfma16(a1f[ks][m], bfr, acc[m]);
        }
#pragma unroll
        for (int m = 0; m < 2; ++m) {
          int rb = 32 * w + 16 * m + 4 * g;
          short pv[4];
#pragma unroll
          for (int r = 0; r < 4; ++r) {
            float v = fmaxf(acc[m][r] + bc[m][r], 0.f) + oc[m][r];
            float o = __shfl_xor(v, 1);
            pv[r] = f2bf(fmaxf(v, o));
          }
          if ((lane & 1) == 0) {
            int t = 8 * n + (lr >> 1);
            *(short4*)((char*)h1t[e] + swz(t, rb * 2)) = make_short4(pv[0], pv[1], pv[2], pv[3]);
          }
        }
      }
    }
  }
  __syncthreads();

  // ---- phase 2: conv2 = 5 shifted GEMMs (M=128, N=2x48, K=128) ----
  f32x4 acc[2][2][3];   // [edge][m][n]
#pragma unroll
  for (int e = 0; e < 2; ++e)
#pragma unroll
    for (int m = 0; m < 2; ++m)
#pragma unroll
      for (int n = 0; n < 3; ++n) acc[e][m][n] = f32x4{0.f, 0.f, 0.f, 0.f};
  {
    const short* a2b = A2 + (32 * w + lr) * 128 + 8 * g;
#pragma unroll
    for (int sh = 0; sh < 5; ++sh) {
#pragma unroll
      for (int ks = 0; ks < 4; ++ks) {
        bf16x8 af0 = *(const bf16x8*)(a2b + sh * 16384 + ks * 32);
        bf16x8 af1 = *(const bf16x8*)(a2b + sh * 16384 + 16 * 128 + ks * 32);
#pragma unroll
        for (int e = 0; e < 2; ++e)
#pragma unroll
          for (int n = 0; n < 3; ++n) {
            bf16x8 bfr = *(const bf16x8*)((char*)h1t[e] + swz(n * 16 + lr + sh, ks * 64 + 16 * g));
            acc[e][0][n] = mfma16(af0, bfr, acc[e][0][n]);
            acc[e][1][n] = mfma16(af1, bfr, acc[e][1][n]);
          }
      }
    }
  }

  // ---- bias/relu/offset in-register + conva logits ----
  {
    f32x4 bc2[2], oc2[2], wam[2];
#pragma unroll
    for (int m = 0; m < 2; ++m) {
      int rb = 32 * w + 16 * m + 4 * g;
      bc2[m] = *(const f32x4*)(b2fv + rb);
      oc2[m] = *(const f32x4*)(o2v + rb);
      wam[m] = *(const f32x4*)(wa + rb);
    }
#pragma unroll
    for (int e = 0; e < 2; ++e)
#pragma unroll
      for (int n = 0; n < 3; ++n) {
        float p = 0.f;
#pragma unroll
        for (int m = 0; m < 2; ++m) {
#pragma unroll
          for (int r = 0; r < 4; ++r) {
            float v = fmaxf(acc[e][m][n][r] + bc2[m][r], 0.f) + oc2[m][r];
            acc[e][m][n][r] = v;          // h2 value, kept f32 in-register
            p += wam[m][r] * v;
          }
        }
        p += __shfl_xor(p, 16);
        p += __shfl_xor(p, 32);
        if (g == 0) lgp[e][w][n * 16 + lr] = p;
      }
  }
  __syncthreads();

  // ---- softmax over t (waves 0,1 handle edge 0,1), fold the /44 of the mean ----
  if (w < 2) {
    int ee = w;
    float x = -3e38f;
    if (lane < 44) x = lgp[ee][0][lane] + lgp[ee][1][lane] + lgp[ee][2][lane] + lgp[ee][3][lane];
    float mx = x;
#pragma unroll
    for (int d = 32; d; d >>= 1) mx = fmaxf(mx, __shfl_xor(mx, d));
    float ex = (lane < 44) ? __expf(x - mx) : 0.f;
    float sm = ex;
#pragma unroll
    for (int d = 32; d; d >>= 1) sm += __shfl_xor(sm, d);
    if (lane < 48) attnS[ee][lane] = (lane < 44) ? ex / (sm * 44.f) : 0.f;
  }
  __syncthreads();

  // ---- attention-weighted pool (in-register) -> ef = hsum ----
#pragma unroll
  for (int e = 0; e < 2; ++e)
#pragma unroll
    for (int m = 0; m < 2; ++m) {
      f32x4 red = f32x4{0.f, 0.f, 0.f, 0.f};
#pragma unroll
      for (int n = 0; n < 3; ++n) {
        float aw = attnS[e][n * 16 + lr];
        red += acc[e][m][n] * aw;
      }
      short pv[4];
#pragma unroll
      for (int r = 0; r < 4; ++r) {
        float p = red[r];
        p += __shfl_xor(p, 1);
        p += __shfl_xor(p, 2);
        p += __shfl_xor(p, 4);
        p += __shfl_xor(p, 8);
        pv[r] = f2bf(p);
      }
      if (lr == 0)
        *(short4*)(ef + (size_t)(eg0 + e) * 128 + 32 * w + 16 * m + 4 * g) =
            make_short4(pv[0], pv[1], pv[2], pv[3]);
    }
}

// ---------------- mlp1 (two-layer, per-edge; L1 weight = folded convp@W1) -> x_skip ----------------
__global__ __launch_bounds__(256, 2) void k_mlp1(
    const short* __restrict__ ef,
    const short* __restrict__ w1t, const float* __restrict__ b1,
    const short* __restrict__ w2t, const float* __restrict__ b2,
    short* __restrict__ xskip)
{
  __shared__ short hbuf[16 * 136];
  __shared__ short obuf[16 * 128];
  const int tid = threadIdx.x, lane = tid & 63, w = tid >> 6, g = lane >> 4, lr = lane & 15;
  const int mbase = blockIdx.x * 16;

  f32x4 acc[2];
  acc[0] = f32x4{0.f, 0.f, 0.f, 0.f};
  acc[1] = f32x4{0.f, 0.f, 0.f, 0.f};
#pragma unroll
  for (int ks = 0; ks < 4; ++ks) {
    bf16x8 afr = *(const bf16x8*)(ef + (size_t)(mbase + lr) * 128 + ks * 32 + 8 * g);
#pragma unroll
    for (int ni = 0; ni < 2; ++ni) {
      int co = (2 * w + ni) * 16 + lr;
      bf16x8 bfr = *(const bf16x8*)(w1t + co * 128 + ks * 32 + 8 * g);
      acc[ni] = mfma16(afr, bfr, acc[ni]);
    }
  }
#pragma unroll
  for (int ni = 0; ni < 2; ++ni) {
    int co = (2 * w + ni) * 16 + lr;
    float bias = b1[co];
#pragma unroll
    for (int r = 0; r < 4; ++r) hbuf[(4 * g + r) * 136 + co] = f2bf(eluf(acc[ni][r] + bias));
  }
  __syncthreads();
  acc[0] = f32x4{0.f, 0.f, 0.f, 0.f};
  acc[1] = f32x4{0.f, 0.f, 0.f, 0.f};
#pragma unroll
  for (int ks = 0; ks < 4; ++ks) {
    bf16x8 afr = *(const bf16x8*)&hbuf[lr * 136 + ks * 32 + 8 * g];
#pragma unroll
    for (int ni = 0; ni < 2; ++ni) {
      int co = (2 * w + ni) * 16 + lr;
      bf16x8 bfr = *(const bf16x8*)(w2t + co * 128 + ks * 32 + 8 * g);
      acc[ni] = mfma16(afr, bfr, acc[ni]);
    }
  }
#pragma unroll
  for (int ni = 0; ni < 2; ++ni) {
    int co = (2 * w + ni) * 16 + lr;
    float bias = b2[co];
#pragma unroll
    for (int r = 0; r < 4; ++r) obuf[(4 * g + r) * 128 + co] = f2bf(eluf(acc[ni][r] + bias));
  }
  __syncthreads();
  *(bf16x8*)(xskip + (size_t)mbase * 128 + tid * 8) = *(const bf16x8*)&obuf[tid * 8];
}

// ---------------- edge2node mean + mlp2 (cooperative edge compaction) ----------------
__global__ __launch_bounds__(128, 4) void k_node(
    const short* __restrict__ xskip, const int* __restrict__ ridx,
    const float* __restrict__ w1, const float* __restrict__ b1,
    const float* __restrict__ w2, const float* __restrict__ b2,
    short* __restrict__ xn)
{
  __shared__ float incs[128];
  __shared__ float hb[128];
  __shared__ int lst[64];
  __shared__ int lcnt;
  const int tid = threadIdx.x;
  const int bn_ = blockIdx.x;
  const int b = bn_ / N_CNT, n = bn_ - b * N_CNT;
  if (tid == 0) lcnt = 0;
  __syncthreads();
  for (int e2 = tid; e2 < E_CNT; e2 += 128) {
    if (ridx[e2] == n) {
      int p = atomicAdd(&lcnt, 1);
      if (p < 64) lst[p] = e2;
    }
  }
  __syncthreads();
  const int m_ = lcnt < 64 ? lcnt : 64;
  const short* base = xskip + (size_t)b * E_CNT * 128 + tid;
  float acc = 0.f;
  for (int i = 0; i < m_; ++i) acc += bf2f(base[(size_t)lst[i] * 128]);
  incs[tid] = acc * 0.025f;  // / N
  __syncthreads();
  float h = b1[tid];
  for (int k = 0; k < 128; ++k) h += incs[k] * w1[k * 128 + tid];
  hb[tid] = eluf(h);
  __syncthreads();
  float h2 = b2[tid];
  for (int k = 0; k < 128; ++k) h2 += hb[k] * w2[k * 128 + tid];
  xn[(size_t)bn_ * 128 + tid] = f2bf(eluf(h2));
}

// ---------------- gather(sn,rc,skip) + mlp3 + fc_out ----------------
__global__ __launch_bounds__(256, 2) void k_final(
    const short* __restrict__ xn, const short* __restrict__ xskip,
    const int* __restrict__ ridx, const int* __restrict__ sidx,
    const short* __restrict__ w1t, const float* __restrict__ b1,
    const short* __restrict__ w2t, const float* __restrict__ b2,
    const float* __restrict__ fcw, const float* __restrict__ fcb,
    float* __restrict__ out)
{
  __shared__ short hbuf[16 * 136];
  __shared__ short h2buf[16 * 136];
  const int tid = threadIdx.x, lane = tid & 63, w = tid >> 6, g = lane >> 4, lr = lane & 15;
  const int mbase = blockIdx.x * 16;
  const int row = mbase + lr;
  const int b = row / E_CNT;
  const int e = row - b * E_CNT;
  const short* aS = xn + (size_t)(b * N_CNT + sidx[e]) * 128;
  const short* aR = xn + (size_t)(b * N_CNT + ridx[e]) * 128;
  const short* aK = xskip + (size_t)row * 128;

  f32x4 acc[2];
  acc[0] = f32x4{0.f, 0.f, 0.f, 0.f};
  acc[1] = f32x4{0.f, 0.f, 0.f, 0.f};
#pragma unroll
  for (int ks = 0; ks < 12; ++ks) {
    int k = ks * 32 + 8 * g;
    const short* ap = (k < 128) ? (aS + k) : (k < 256) ? (aR + (k - 128)) : (aK + (k - 256));
    bf16x8 afr = *(const bf16x8*)ap;
#pragma unroll
    for (int ni = 0; ni < 2; ++ni) {
      int co = (2 * w + ni) * 16 + lr;
      bf16x8 bfr = *(const bf16x8*)(w1t + co * 384 + ks * 32 + 8 * g);
      acc[ni] = mfma16(afr, bfr, acc[ni]);
    }
  }
#pragma unroll
  for (int ni = 0; ni < 2; ++ni) {
    int co = (2 * w + ni) * 16 + lr;
    float bias = b1[co];
#pragma unroll
    for (int r = 0; r < 4; ++r) hbuf[(4 * g + r) * 136 + co] = f2bf(eluf(acc[ni][r] + bias));
  }
  __syncthreads();
  acc[0] = f32x4{0.f, 0.f, 0.f, 0.f};
  acc[1] = f32x4{0.f, 0.f, 0.f, 0.f};
#pragma unroll
  for (int ks = 0; ks < 4; ++ks) {
    bf16x8 afr = *(const bf16x8*)&hbuf[lr * 136 + ks * 32 + 8 * g];
#pragma unroll
    for (int ni = 0; ni < 2; ++ni) {
      int co = (2 * w + ni) * 16 + lr;
      bf16x8 bfr = *(const bf16x8*)(w2t + co * 128 + ks * 32 + 8 * g);
      acc[ni] = mfma16(afr, bfr, acc[ni]);
    }
  }
#pragma unroll
  for (int ni = 0; ni < 2; ++ni) {
    int co = (2 * w + ni) * 16 + lr;
    float bias = b2[co];
#pragma unroll
    for (int r = 0; r < 4; ++r) h2buf[(4 * g + r) * 136 + co] = f2bf(eluf(acc[ni][r] + bias));
  }
  __syncthreads();
  if (tid < 32) {
    int e2 = tid >> 1, o = tid & 1;
    float s = fcb[o];
    for (int k = 0; k < 128; ++k) s += bf2f(h2buf[e2 * 136 + k]) * fcw[k * 2 + o];
    out[(size_t)(mbase + e2) * 2 + o] = s;
  }
}

extern "C" void kernel_launch(void* const* d_in, const int* in_sizes, int n_in,
                              void* d_out, int out_size, void* d_ws, size_t ws_size,
                              hipStream_t stream) {
  (void)in_sizes; (void)n_in; (void)out_size; (void)ws_size;
  const float* inp  = (const float*)d_in[0];
  const float* relr = (const float*)d_in[1];
  const float* rels = (const float*)d_in[2];
  const float* c1w  = (const float*)d_in[3];
  const float* c1b  = (const float*)d_in[4];
  const float* g1   = (const float*)d_in[5];
  const float* be1  = (const float*)d_in[6];
  const float* m1   = (const float*)d_in[7];
  const float* v1   = (const float*)d_in[8];
  const float* c2w  = (const float*)d_in[9];
  const float* c2b  = (const float*)d_in[10];
  const float* g2   = (const float*)d_in[11];
  const float* be2  = (const float*)d_in[12];
  const float* m2   = (const float*)d_in[13];
  const float* v2   = (const float*)d_in[14];
  const float* cpw  = (const float*)d_in[15];
  const float* cpb  = (const float*)d_in[16];
  const float* caw  = (const float*)d_in[17];
  // d_in[18] = conva_b: softmax shift-invariant, unused
  const float* m1w1 = (const float*)d_in[19];
  const float* m1b1 = (const float*)d_in[20];
  const float* m1w2 = (const float*)d_in[21];
  const float* m1b2 = (const float*)d_in[22];
  const float* m2w1 = (const float*)d_in[23];
  const float* m2b1 = (const float*)d_in[24];
  const float* m2w2 = (const float*)d_in[25];
  const float* m2b2 = (const float*)d_in[26];
  const float* m3w1 = (const float*)d_in[27];
  const float* m3b1 = (const float*)d_in[28];
  const float* m3w2 = (const float*)d_in[29];
  const float* m3b2 = (const float*)d_in[30];
  const float* fcw  = (const float*)d_in[31];
  const float* fcb  = (const float*)d_in[32];
  float* out = (float*)d_out;

  char* ws = (char*)d_ws;
  short* A1   = (short*)(ws + OFF_A1);
  short* A2   = (short*)(ws + OFF_A2);
  short* inpb = (short*)(ws + OFF_INPB);
  float* b1f  = (float*)(ws + OFF_B1F);
  float* o1   = (float*)(ws + OFF_O1);
  float* b2f  = (float*)(ws + OFF_B2F);
  float* o2   = (float*)(ws + OFF_O2);
  float* bc1  = (float*)(ws + OFF_BC1);
  short* w1t1 = (short*)(ws + OFF_W1T1);
  short* w1t2 = (short*)(ws + OFF_W1T2);
  short* w3t1 = (short*)(ws + OFF_W3T1);
  short* w3t2 = (short*)(ws + OFF_W3T2);
  int*   ridx = (int*)(ws + OFF_RIDX);
  int*   sidx = (int*)(ws + OFF_SIDX);
  short* ef   = (short*)(ws + OFF_EF);
  short* xsk  = (short*)(ws + OFF_XSK);
  short* xn   = (short*)(ws + OFF_XN);

  k_prep<<<256, 256, 0, stream>>>(inp, c1w, c1b, c2w, c2b, cpw, cpb,
                                  g1, be1, m1, v1, g2, be2, m2, v2,
                                  m1w1, m1b1, m1w2, m3w1, m3w2, relr, rels,
                                  A1, A2, inpb, b1f, o1, b2f, o2, bc1,
                                  w1t1, w1t2, w3t1, w3t2, ridx, sidx);
  k_cnn<<<B_CNT * E_CNT / 2, 256, 0, stream>>>(inpb, A1, A2, b1f, o1, b2f, o2,
                                               caw, ridx, sidx, ef);
  k_mlp1<<<390, 256, 0, stream>>>(ef, w1t1, bc1, w1t2, m1b2, xsk);
  k_node<<<B_CNT * N_CNT, 128, 0, stream>>>(xsk, ridx, m2w1, m2b1, m2w2, m2b2, xn);
  k_final<<<390, 256, 0, stream>>>(xn, xsk, ridx, sidx, w3t1, m3b1, w3t2, m3b2, fcw, fcb, out);
}

// Round 7
// 127.062 us; speedup vs baseline: 1.5268x; 1.0380x over previous
//
#include <hip/hip_runtime.h>

#define E_CNT 1560
#define B_CNT 4
#define N_CNT 40
#define T_CNT 100

typedef __attribute__((ext_vector_type(8))) short bf16x8;
typedef __attribute__((ext_vector_type(4))) float f32x4;

__device__ __forceinline__ short f2bf(float f) {
  union { float f; unsigned u; } v; v.f = f;
  unsigned r = v.u + 0x7FFFu + ((v.u >> 16) & 1u);
  return (short)(r >> 16);
}
__device__ __forceinline__ float bf2f(short s) {
  union { unsigned u; float f; } v; v.u = ((unsigned)(unsigned short)s) << 16;
  return v.f;
}
// packed f32x2 -> bf16x2 (RNE), one VALU instr
__device__ __forceinline__ int cvtpk(float lo, float hi) {
  int r;
  asm("v_cvt_pk_bf16_f32 %0, %1, %2" : "=v"(r) : "v"(lo), "v"(hi));
  return r;
}
__device__ __forceinline__ float eluf(float x) { return x > 0.f ? x : (__expf(x) - 1.f); }
__device__ __forceinline__ f32x4 mfma16(bf16x8 a, bf16x8 b, f32x4 c) {
  return __builtin_amdgcn_mfma_f32_16x16x32_bf16(a, b, c, 0, 0, 0);
}
// T2 XOR swizzle: 256B rows, 16B slots permuted by row&7 (write & read both sides)
__device__ __forceinline__ int swz(int row, int bytecol) {
  return row * 256 + (bytecol ^ ((row & 7) << 4));
}

// ---------------- workspace layout (bytes) ----------------
enum : size_t {
  OFF_A1   = 0,                     // [128][64] bf16 conv1 A (bn1 scale folded), col = tap*8+c
  OFF_A2   = OFF_A1 + 16384,        // [5][128][128] bf16 conv2 shifted A (bn2 scale folded)
  OFF_INPB = OFF_A2 + 163840,       // [4*40*100*4] bf16 pre-converted input
  OFF_B1F  = OFF_INPB + 128000,     // [128] f32 folded conv1 bias (sc1*b1)
  OFF_O1   = OFF_B1F + 512,         // [128] f32 bn1 offset
  OFF_B2F  = OFF_O1 + 512,          // [128] f32 folded conv2 bias (sc2*b2)
  OFF_O2   = OFF_B2F + 512,         // [128] f32 bn2 offset
  OFF_BC1  = OFF_O2 + 512,          // [128] f32 folded mlp1 layer-1 bias
  OFF_W1T1 = OFF_BC1 + 512,         // [128][128] bf16 Wc^T = (convp_w^T @ mlp1_w1)^T
  OFF_W1T2 = OFF_W1T1 + 32768,      // [128][128] bf16 mlp1_w2^T
  OFF_W3T1 = OFF_W1T2 + 32768,      // [128][384] bf16 mlp3_w1^T
  OFF_W3T2 = OFF_W3T1 + 98304,      // [128][128] bf16 mlp3_w2^T
  OFF_RIDX = OFF_W3T2 + 32768,      // [1560] int
  OFF_SIDX = OFF_RIDX + 6400,
  OFF_EF   = OFF_SIDX + 6400,       // [6240][128] bf16 attention-pooled h2 (hsum)
  OFF_XSK  = OFF_EF + 1597440,      // [6240][128] bf16 x_skip
  OFF_XN   = OFF_XSK + 1597440,     // [160][128] bf16 node features
  WS_NEED  = OFF_XN + 40960
};

// ---------------- prep: repack weights, fold BN scale+convp, cvt input, decode edges ----------------
__global__ void k_prep(
    const float* __restrict__ inp,
    const float* __restrict__ c1w, const float* __restrict__ c1b,
    const float* __restrict__ c2w, const float* __restrict__ c2b,
    const float* __restrict__ cpw, const float* __restrict__ cpb,
    const float* __restrict__ g1, const float* __restrict__ be1, const float* __restrict__ m1, const float* __restrict__ v1,
    const float* __restrict__ g2, const float* __restrict__ be2, const float* __restrict__ m2, const float* __restrict__ v2,
    const float* __restrict__ m1w1, const float* __restrict__ m1b1, const float* __restrict__ m1w2,
    const float* __restrict__ m3w1, const float* __restrict__ m3w2,
    const float* __restrict__ relr, const float* __restrict__ rels,
    short* __restrict__ A1, short* __restrict__ A2, short* __restrict__ inpb,
    float* __restrict__ b1f, float* __restrict__ o1, float* __restrict__ b2f, float* __restrict__ o2,
    float* __restrict__ bc1,
    short* __restrict__ w1t1, short* __restrict__ w1t2, short* __restrict__ w3t1, short* __restrict__ w3t2,
    int* __restrict__ ridx, int* __restrict__ sidx)
{
  const int id = blockIdx.x * blockDim.x + threadIdx.x;
  const int NTH = gridDim.x * blockDim.x;
  // conv1 A with bn1 scale folded: col = tap*8 + c (cols with tap>=5 are zero)
  for (int i = id; i < 8192; i += NTH) {
    int co = i >> 6, col = i & 63, k = col >> 3, c = col & 7;
    float sa = g1[co] * rsqrtf(v1[co] + 1e-5f);
    A1[i] = (k < 5) ? f2bf(c1w[co * 40 + c * 5 + k] * sa) : (short)0;
  }
  // conv2 A with bn2 scale folded
  for (int i = id; i < 81920; i += NTH) {
    int s = i >> 14, rem = i & 16383, co = rem >> 7, ci = rem & 127;
    float sb = g2[co] * rsqrtf(v2[co] + 1e-5f);
    A2[i] = f2bf(c2w[(co * 128 + ci) * 5 + s] * sb);
  }
  for (int i = id; i < 64000; i += NTH) inpb[i] = f2bf(inp[i]);
  for (int i = id; i < 128; i += NTH) {
    float sa = g1[i] * rsqrtf(v1[i] + 1e-5f);
    b1f[i] = c1b[i] * sa; o1[i] = be1[i] - m1[i] * sa;
    float sb = g2[i] * rsqrtf(v2[i] + 1e-5f);
    b2f[i] = c2b[i] * sb; o2[i] = be2[i] - m2[i] * sb;
  }
  // Wc^T: w1t1[c*128+i] = sum_o cpw[o*128+i] * m1w1[o*128+c]  (convp folded into mlp1 L1)
  for (int idx = id; idx < 16384; idx += NTH) {
    int c = idx >> 7, i = idx & 127;
    float s = 0.f;
    for (int o = 0; o < 128; ++o) s += cpw[o * 128 + i] * m1w1[o * 128 + c];
    w1t1[idx] = f2bf(s);
  }
  // bc1[c] = m1b1[c] + (1/44) * sum_o cpb[o] * m1w1[o*128+c]
  for (int c = id; c < 128; c += NTH) {
    float s = 0.f;
    for (int o = 0; o < 128; ++o) s += cpb[o] * m1w1[o * 128 + c];
    bc1[c] = m1b1[c] + s * (1.0f / 44.0f);
  }
  for (int i = id; i < 16384; i += NTH) {
    int co = i >> 7, k = i & 127;
    w1t2[i] = f2bf(m1w2[k * 128 + co]);
    w3t2[i] = f2bf(m3w2[k * 128 + co]);
  }
  for (int i = id; i < 49152; i += NTH) {
    int co = i / 384, k = i - co * 384;
    w3t1[i] = f2bf(m3w1[k * 128 + co]);
  }
  for (int i = id; i < E_CNT; i += NTH) {
    int rr = 0, ss = 0;
    for (int n = 0; n < N_CNT; ++n) {
      if (relr[i * N_CNT + n] > 0.5f) rr = n;
      if (rels[i * N_CNT + n] > 0.5f) ss = n;
    }
    ridx[i] = rr; sidx[i] = ss;
  }
}

// ---------------- fused per-edge temporal CNN: 2 edges/block, m=2 per wave ----------------
__global__ __launch_bounds__(256, 5) void k_cnn(
    const short* __restrict__ inpb,
    const short* __restrict__ A1, const short* __restrict__ A2,
    const float* __restrict__ b1fv, const float* __restrict__ o1v,
    const float* __restrict__ b2fv, const float* __restrict__ o2v,
    const float* __restrict__ wa,
    const int* __restrict__ ridx, const int* __restrict__ sidx,
    short* __restrict__ ef)
{
  __shared__ short h1t[2][52 * 128];   // pooled conv1 out [t][ci], XOR-swizzled, rows 48-51 pad
  __shared__ short rawb[4 * 408];      // staged node series [S0|R0|S1|R1][400] (+8 pad)
  __shared__ float lgp[2][4][48];      // conva logit partials per (edge, wave)
  __shared__ float attnS[2][48];       // softmax/44 weights

  const int tid = threadIdx.x;
  const int lane = tid & 63;
  const int w = tid >> 6;
  const int g = lane >> 4;
  const int lr = lane & 15;

  const int eg0 = blockIdx.x * 2;
  const int b = eg0 / E_CNT;
  const int e0 = eg0 - b * E_CNT;
  const short* nbase = inpb + (size_t)b * N_CNT * 400;

  // ---- phase 0: stage 4 node rows (3.2 KB) into LDS with coalesced 16B loads ----
  if (tid < 200) {
    int row = tid / 50, off = (tid % 50) * 8;
    int e = row >> 1;
    int node = (row & 1) ? ridx[e0 + e] : sidx[e0 + e];
    *(bf16x8*)&rawb[row * 408 + off] = *(const bf16x8*)(nbase + node * 400 + off);
  }
  // zero pad rows 48-51 of both h1t (ordered by the staging barrier below)
  {
    int ee = tid >> 7, off = (tid & 127) * 4;
    *(short4*)&h1t[ee][48 * 128 + off] = make_short4(0, 0, 0, 0);
  }
  __syncthreads();

  // ---- phase 1: conv1 (scale-folded) + relu + offset + maxpool2 -> h1t[e] ----
  {
    bf16x8 a1f[2][2];
#pragma unroll
    for (int ks = 0; ks < 2; ++ks)
#pragma unroll
      for (int m = 0; m < 2; ++m)
        a1f[ks][m] = *(const bf16x8*)(A1 + (32 * w + 16 * m + lr) * 64 + ks * 32 + 8 * g);
    f32x4 bc[2], oc[2];
#pragma unroll
    for (int m = 0; m < 2; ++m) {
      int rb = 32 * w + 16 * m + 4 * g;
      bc[m] = *(const f32x4*)(b1fv + rb);
      oc[m] = *(const f32x4*)(o1v + rb);
    }
#pragma unroll
    for (int e = 0; e < 2; ++e) {
#pragma unroll
      for (int n = 0; n < 6; ++n) {
        f32x4 acc[2];
        acc[0] = f32x4{0.f, 0.f, 0.f, 0.f};
        acc[1] = f32x4{0.f, 0.f, 0.f, 0.f};
#pragma unroll
        for (int ks = 0; ks < 2; ++ks) {
          int tc = n * 16 + lr + 4 * ks + g;   // tap = 4ks+g; taps 5-7 hit zero A cols
          tc = tc > 99 ? 99 : tc;
          union { bf16x8 v; int2 h[2]; } u;    // concat S||R, zero VALU
          u.h[0] = *(const int2*)&rawb[(2 * e) * 408 + tc * 4];
          u.h[1] = *(const int2*)&rawb[(2 * e + 1) * 408 + tc * 4];
#pragma unroll
          for (int m = 0; m < 2; ++m) acc[m] = mfma16(a1f[ks][m], u.v, acc[m]);
        }
#pragma unroll
        for (int m = 0; m < 2; ++m) {
          int rb = 32 * w + 16 * m + 4 * g;
          float p[4];
#pragma unroll
          for (int r = 0; r < 4; ++r) {
            float v = fmaxf(acc[m][r] + bc[m][r], 0.f) + oc[m][r];
            float o = __shfl_xor(v, 1);
            p[r] = fmaxf(v, o);
          }
          int lo = cvtpk(p[0], p[1]), hi = cvtpk(p[2], p[3]);
          if ((lane & 1) == 0) {
            int t = 8 * n + (lr >> 1);
            *(int2*)((char*)h1t[e] + swz(t, rb * 2)) = make_int2(lo, hi);
          }
        }
      }
    }
  }
  __syncthreads();

  // ---- phase 2: conv2 = 5 shifted GEMMs (M=128, N=2x48, K=128), hoisted swizzle bases ----
  f32x4 acc[2][2][3];   // [edge][m][n]
#pragma unroll
  for (int e = 0; e < 2; ++e)
#pragma unroll
    for (int m = 0; m < 2; ++m)
#pragma unroll
      for (int n = 0; n < 3; ++n) acc[e][m][n] = f32x4{0.f, 0.f, 0.f, 0.f};
  {
    const short* a2b = A2 + (32 * w + lr) * 128 + 8 * g;
    const int c0 = 16 * g;
#pragma unroll
    for (int sh = 0; sh < 5; ++sh) {
      const int rowb = (lr + sh) * 256;          // row = n*16+lr+sh; n*16 folds to imm offset
      const int xr = ((lr + sh) & 7) << 4;       // n- and ks-invariant swizzle term
#pragma unroll
      for (int ks = 0; ks < 4; ++ks) {
        bf16x8 af0 = *(const bf16x8*)(a2b + sh * 16384 + ks * 32);
        bf16x8 af1 = *(const bf16x8*)(a2b + sh * 16384 + 16 * 128 + ks * 32);
        const char* p0 = (const char*)h1t[0] + (rowb + ((ks * 64 + c0) ^ xr));
#pragma unroll
        for (int e = 0; e < 2; ++e) {
          const char* pe = p0 + e * 13312;       // sizeof(h1t[0])
#pragma unroll
          for (int n = 0; n < 3; ++n) {
            bf16x8 bfr = *(const bf16x8*)(pe + n * 4096);
            acc[e][0][n] = mfma16(af0, bfr, acc[e][0][n]);
            acc[e][1][n] = mfma16(af1, bfr, acc[e][1][n]);
          }
        }
      }
    }
  }

  // ---- bias/relu/offset in-register + conva logits ----
  {
    f32x4 bc2[2], oc2[2], wam[2];
#pragma unroll
    for (int m = 0; m < 2; ++m) {
      int rb = 32 * w + 16 * m + 4 * g;
      bc2[m] = *(const f32x4*)(b2fv + rb);
      oc2[m] = *(const f32x4*)(o2v + rb);
      wam[m] = *(const f32x4*)(wa + rb);
    }
#pragma unroll
    for (int e = 0; e < 2; ++e)
#pragma unroll
      for (int n = 0; n < 3; ++n) {
        float p = 0.f;
#pragma unroll
        for (int m = 0; m < 2; ++m) {
#pragma unroll
          for (int r = 0; r < 4; ++r) {
            float v = fmaxf(acc[e][m][n][r] + bc2[m][r], 0.f) + oc2[m][r];
            acc[e][m][n][r] = v;          // h2 value, kept f32 in-register
            p += wam[m][r] * v;
          }
        }
        p += __shfl_xor(p, 16);
        p += __shfl_xor(p, 32);
        if (g == 0) lgp[e][w][n * 16 + lr] = p;
      }
  }
  __syncthreads();

  // ---- softmax over t (waves 0,1 handle edge 0,1), fold the /44 of the mean ----
  if (w < 2) {
    int ee = w;
    float x = -3e38f;
    if (lane < 44) x = lgp[ee][0][lane] + lgp[ee][1][lane] + lgp[ee][2][lane] + lgp[ee][3][lane];
    float mx = x;
#pragma unroll
    for (int d = 32; d; d >>= 1) mx = fmaxf(mx, __shfl_xor(mx, d));
    float ex = (lane < 44) ? __expf(x - mx) : 0.f;
    float sm = ex;
#pragma unroll
    for (int d = 32; d; d >>= 1) sm += __shfl_xor(sm, d);
    if (lane < 48) attnS[ee][lane] = (lane < 44) ? ex / (sm * 44.f) : 0.f;
  }
  __syncthreads();

  // ---- attention-weighted pool (in-register) -> ef = hsum ----
#pragma unroll
  for (int e = 0; e < 2; ++e)
#pragma unroll
    for (int m = 0; m < 2; ++m) {
      f32x4 red = f32x4{0.f, 0.f, 0.f, 0.f};
#pragma unroll
      for (int n = 0; n < 3; ++n) {
        float aw = attnS[e][n * 16 + lr];
        red += acc[e][m][n] * aw;
      }
      float p[4];
#pragma unroll
      for (int r = 0; r < 4; ++r) {
        float q = red[r];
        q += __shfl_xor(q, 1);
        q += __shfl_xor(q, 2);
        q += __shfl_xor(q, 4);
        q += __shfl_xor(q, 8);
        p[r] = q;
      }
      int lo = cvtpk(p[0], p[1]), hi = cvtpk(p[2], p[3]);
      if (lr == 0)
        *(int2*)(ef + (size_t)(eg0 + e) * 128 + 32 * w + 16 * m + 4 * g) = make_int2(lo, hi);
    }
}

// ---------------- mlp1 (two-layer, per-edge; L1 weight = folded convp@W1) -> x_skip ----------------
__global__ __launch_bounds__(256, 2) void k_mlp1(
    const short* __restrict__ ef,
    const short* __restrict__ w1t, const float* __restrict__ b1,
    const short* __restrict__ w2t, const float* __restrict__ b2,
    short* __restrict__ xskip)
{
  __shared__ short hbuf[16 * 136];
  __shared__ short obuf[16 * 128];
  const int tid = threadIdx.x, lane = tid & 63, w = tid >> 6, g = lane >> 4, lr = lane & 15;
  const int mbase = blockIdx.x * 16;

  f32x4 acc[2];
  acc[0] = f32x4{0.f, 0.f, 0.f, 0.f};
  acc[1] = f32x4{0.f, 0.f, 0.f, 0.f};
#pragma unroll
  for (int ks = 0; ks < 4; ++ks) {
    bf16x8 afr = *(const bf16x8*)(ef + (size_t)(mbase + lr) * 128 + ks * 32 + 8 * g);
#pragma unroll
    for (int ni = 0; ni < 2; ++ni) {
      int co = (2 * w + ni) * 16 + lr;
      bf16x8 bfr = *(const bf16x8*)(w1t + co * 128 + ks * 32 + 8 * g);
      acc[ni] = mfma16(afr, bfr, acc[ni]);
    }
  }
#pragma unroll
  for (int ni = 0; ni < 2; ++ni) {
    int co = (2 * w + ni) * 16 + lr;
    float bias = b1[co];
#pragma unroll
    for (int r = 0; r < 4; ++r) hbuf[(4 * g + r) * 136 + co] = f2bf(eluf(acc[ni][r] + bias));
  }
  __syncthreads();
  acc[0] = f32x4{0.f, 0.f, 0.f, 0.f};
  acc[1] = f32x4{0.f, 0.f, 0.f, 0.f};
#pragma unroll
  for (int ks = 0; ks < 4; ++ks) {
    bf16x8 afr = *(const bf16x8*)&hbuf[lr * 136 + ks * 32 + 8 * g];
#pragma unroll
    for (int ni = 0; ni < 2; ++ni) {
      int co = (2 * w + ni) * 16 + lr;
      bf16x8 bfr = *(const bf16x8*)(w2t + co * 128 + ks * 32 + 8 * g);
      acc[ni] = mfma16(afr, bfr, acc[ni]);
    }
  }
#pragma unroll
  for (int ni = 0; ni < 2; ++ni) {
    int co = (2 * w + ni) * 16 + lr;
    float bias = b2[co];
#pragma unroll
    for (int r = 0; r < 4; ++r) obuf[(4 * g + r) * 128 + co] = f2bf(eluf(acc[ni][r] + bias));
  }
  __syncthreads();
  *(bf16x8*)(xskip + (size_t)mbase * 128 + tid * 8) = *(const bf16x8*)&obuf[tid * 8];
}

// ---------------- edge2node mean + mlp2 (cooperative edge compaction) ----------------
__global__ __launch_bounds__(128, 4) void k_node(
    const short* __restrict__ xskip, const int* __restrict__ ridx,
    const float* __restrict__ w1, const float* __restrict__ b1,
    const float* __restrict__ w2, const float* __restrict__ b2,
    short* __restrict__ xn)
{
  __shared__ float incs[128];
  __shared__ float hb[128];
  __shared__ int lst[64];
  __shared__ int lcnt;
  const int tid = threadIdx.x;
  const int bn_ = blockIdx.x;
  const int b = bn_ / N_CNT, n = bn_ - b * N_CNT;
  if (tid == 0) lcnt = 0;
  __syncthreads();
  for (int e2 = tid; e2 < E_CNT; e2 += 128) {
    if (ridx[e2] == n) {
      int p = atomicAdd(&lcnt, 1);
      if (p < 64) lst[p] = e2;
    }
  }
  __syncthreads();
  const int m_ = lcnt < 64 ? lcnt : 64;
  const short* base = xskip + (size_t)b * E_CNT * 128 + tid;
  float acc = 0.f;
  for (int i = 0; i < m_; ++i) acc += bf2f(base[(size_t)lst[i] * 128]);
  incs[tid] = acc * 0.025f;  // / N
  __syncthreads();
  float h = b1[tid];
  for (int k = 0; k < 128; ++k) h += incs[k] * w1[k * 128 + tid];
  hb[tid] = eluf(h);
  __syncthreads();
  float h2 = b2[tid];
  for (int k = 0; k < 128; ++k) h2 += hb[k] * w2[k * 128 + tid];
  xn[(size_t)bn_ * 128 + tid] = f2bf(eluf(h2));
}

// ---------------- gather(sn,rc,skip) + mlp3 + fc_out ----------------
__global__ __launch_bounds__(256, 2) void k_final(
    const short* __restrict__ xn, const short* __restrict__ xskip,
    const int* __restrict__ ridx, const int* __restrict__ sidx,
    const short* __restrict__ w1t, const float* __restrict__ b1,
    const short* __restrict__ w2t, const float* __restrict__ b2,
    const float* __restrict__ fcw, const float* __restrict__ fcb,
    float* __restrict__ out)
{
  __shared__ short hbuf[16 * 136];
  __shared__ short h2buf[16 * 136];
  const int tid = threadIdx.x, lane = tid & 63, w = tid >> 6, g = lane >> 4, lr = lane & 15;
  const int mbase = blockIdx.x * 16;
  const int row = mbase + lr;
  const int b = row / E_CNT;
  const int e = row - b * E_CNT;
  const short* aS = xn + (size_t)(b * N_CNT + sidx[e]) * 128;
  const short* aR = xn + (size_t)(b * N_CNT + ridx[e]) * 128;
  const short* aK = xskip + (size_t)row * 128;

  f32x4 acc[2];
  acc[0] = f32x4{0.f, 0.f, 0.f, 0.f};
  acc[1] = f32x4{0.f, 0.f, 0.f, 0.f};
#pragma unroll
  for (int ks = 0; ks < 12; ++ks) {
    int k = ks * 32 + 8 * g;
    const short* ap = (k < 128) ? (aS + k) : (k < 256) ? (aR + (k - 128)) : (aK + (k - 256));
    bf16x8 afr = *(const bf16x8*)ap;
#pragma unroll
    for (int ni = 0; ni < 2; ++ni) {
      int co = (2 * w + ni) * 16 + lr;
      bf16x8 bfr = *(const bf16x8*)(w1t + co * 384 + ks * 32 + 8 * g);
      acc[ni] = mfma16(afr, bfr, acc[ni]);
    }
  }
#pragma unroll
  for (int ni = 0; ni < 2; ++ni) {
    int co = (2 * w + ni) * 16 + lr;
    float bias = b1[co];
#pragma unroll
    for (int r = 0; r < 4; ++r) hbuf[(4 * g + r) * 136 + co] = f2bf(eluf(acc[ni][r] + bias));
  }
  __syncthreads();
  acc[0] = f32x4{0.f, 0.f, 0.f, 0.f};
  acc[1] = f32x4{0.f, 0.f, 0.f, 0.f};
#pragma unroll
  for (int ks = 0; ks < 4; ++ks) {
    bf16x8 afr = *(const bf16x8*)&hbuf[lr * 136 + ks * 32 + 8 * g];
#pragma unroll
    for (int ni = 0; ni < 2; ++ni) {
      int co = (2 * w + ni) * 16 + lr;
      bf16x8 bfr = *(const bf16x8*)(w2t + co * 128 + ks * 32 + 8 * g);
      acc[ni] = mfma16(afr, bfr, acc[ni]);
    }
  }
#pragma unroll
  for (int ni = 0; ni < 2; ++ni) {
    int co = (2 * w + ni) * 16 + lr;
    float bias = b2[co];
#pragma unroll
    for (int r = 0; r < 4; ++r) h2buf[(4 * g + r) * 136 + co] = f2bf(eluf(acc[ni][r] + bias));
  }
  __syncthreads();
  if (tid < 32) {
    int e2 = tid >> 1, o = tid & 1;
    float s = fcb[o];
    for (int k = 0; k < 128; ++k) s += bf2f(h2buf[e2 * 136 + k]) * fcw[k * 2 + o];
    out[(size_t)(mbase + e2) * 2 + o] = s;
  }
}

extern "C" void kernel_launch(void* const* d_in, const int* in_sizes, int n_in,
                              void* d_out, int out_size, void* d_ws, size_t ws_size,
                              hipStream_t stream) {
  (void)in_sizes; (void)n_in; (void)out_size; (void)ws_size;
  const float* inp  = (const float*)d_in[0];
  const float* relr = (const float*)d_in[1];
  const float* rels = (const float*)d_in[2];
  const float* c1w  = (const float*)d_in[3];
  const float* c1b  = (const float*)d_in[4];
  const float* g1   = (const float*)d_in[5];
  const float* be1  = (const float*)d_in[6];
  const float* m1   = (const float*)d_in[7];
  const float* v1   = (const float*)d_in[8];
  const float* c2w  = (const float*)d_in[9];
  const float* c2b  = (const float*)d_in[10];
  const float* g2   = (const float*)d_in[11];
  const float* be2  = (const float*)d_in[12];
  const float* m2   = (const float*)d_in[13];
  const float* v2   = (const float*)d_in[14];
  const float* cpw  = (const float*)d_in[15];
  const float* cpb  = (const float*)d_in[16];
  const float* caw  = (const float*)d_in[17];
  // d_in[18] = conva_b: softmax shift-invariant, unused
  const float* m1w1 = (const float*)d_in[19];
  const float* m1b1 = (const float*)d_in[20];
  const float* m1w2 = (const float*)d_in[21];
  const float* m1b2 = (const float*)d_in[22];
  const float* m2w1 = (const float*)d_in[23];
  const float* m2b1 = (const float*)d_in[24];
  const float* m2w2 = (const float*)d_in[25];
  const float* m2b2 = (const float*)d_in[26];
  const float* m3w1 = (const float*)d_in[27];
  const float* m3b1 = (const float*)d_in[28];
  const float* m3w2 = (const float*)d_in[29];
  const float* m3b2 = (const float*)d_in[30];
  const float* fcw  = (const float*)d_in[31];
  const float* fcb  = (const float*)d_in[32];
  float* out = (float*)d_out;

  char* ws = (char*)d_ws;
  short* A1   = (short*)(ws + OFF_A1);
  short* A2   = (short*)(ws + OFF_A2);
  short* inpb = (short*)(ws + OFF_INPB);
  float* b1f  = (float*)(ws + OFF_B1F);
  float* o1   = (float*)(ws + OFF_O1);
  float* b2f  = (float*)(ws + OFF_B2F);
  float* o2   = (float*)(ws + OFF_O2);
  float* bc1  = (float*)(ws + OFF_BC1);
  short* w1t1 = (short*)(ws + OFF_W1T1);
  short* w1t2 = (short*)(ws + OFF_W1T2);
  short* w3t1 = (short*)(ws + OFF_W3T1);
  short* w3t2 = (short*)(ws + OFF_W3T2);
  int*   ridx = (int*)(ws + OFF_RIDX);
  int*   sidx = (int*)(ws + OFF_SIDX);
  short* ef   = (short*)(ws + OFF_EF);
  short* xsk  = (short*)(ws + OFF_XSK);
  short* xn   = (short*)(ws + OFF_XN);

  k_prep<<<256, 256, 0, stream>>>(inp, c1w, c1b, c2w, c2b, cpw, cpb,
                                  g1, be1, m1, v1, g2, be2, m2, v2,
                                  m1w1, m1b1, m1w2, m3w1, m3w2, relr, rels,
                                  A1, A2, inpb, b1f, o1, b2f, o2, bc1,
                                  w1t1, w1t2, w3t1, w3t2, ridx, sidx);
  k_cnn<<<B_CNT * E_CNT / 2, 256, 0, stream>>>(inpb, A1, A2, b1f, o1, b2f, o2,
                                               caw, ridx, sidx, ef);
  k_mlp1<<<390, 256, 0, stream>>>(ef, w1t1, bc1, w1t2, m1b2, xsk);
  k_node<<<B_CNT * N_CNT, 128, 0, stream>>>(xsk, ridx, m2w1, m2b1, m2w2, m2b2, xn);
  k_final<<<390, 256, 0, stream>>>(xn, xsk, ridx, sidx, w3t1, m3b1, w3t2, m3b2, fcw, fcb, out);
}